// Round 11
// baseline (1661.001 us; speedup 1.0000x reference)
//
#include <hip/hip_runtime.h>
#include <hip/hip_bf16.h>
#include <math.h>

#define TTOK 8192
#define DDIM 1024
#define HDIM 4096
#define NEXP 8
#define BMT 256              // slot padding granularity per expert
#define MAXT 72              // sum ceil(c_e/256) <= 16384/256 + 8
#define MAXSLOTS (MAXT * BMT)

typedef __bf16 bf16x8 __attribute__((ext_vector_type(8)));
typedef float f32x4 __attribute__((ext_vector_type(4)));
typedef const void __attribute__((address_space(1))) *gvp_t;
typedef void __attribute__((address_space(3))) *lvp_t;

__device__ __forceinline__ void gload16(const void *g, void *l) {
  __builtin_amdgcn_global_load_lds((gvp_t)g, (lvp_t)l, 16, 0, 0);
}

// fast exact-erf GELU: Abramowitz-Stegun 7.1.26, |err(erf)| <= 1.5e-7
__device__ __forceinline__ float gelu_f(float v) {
  const float z = v * 0.70710678118654752f;
  const float az = fabsf(z);
  const float t = __builtin_amdgcn_rcpf(fmaf(0.3275911f, az, 1.0f));
  float p = fmaf(1.061405429f, t, -1.453152027f);
  p = fmaf(p, t, 1.421413741f);
  p = fmaf(p, t, -0.284496736f);
  p = fmaf(p, t, 0.254829592f);
  p *= t;
  const float ez = __builtin_amdgcn_exp2f(az * az * -1.4426950408889634f);
  float r = fmaf(-p, ez, 1.0f);          // erf(|z|)
  r = (v < 0.f) ? -r : r;                // erf(z)
  return 0.5f * v * (1.0f + r);
}

// ---------------- small utility kernels ----------------

__global__ __launch_bounds__(64) void zero_meta(int *counts, int *cursors, float *probsum) {
  int i = threadIdx.x;
  if (i < NEXP) { counts[i] = 0; cursors[i] = 0; probsum[i] = 0.f; }
}

// src [E][R][C] fp32 -> dst [E][C][R] bf16, 64x64 LDS tiles.
// Writes vectorized: uint2 = 4 bf16 per lane (G13); LDS reads <=2-way (free).
__global__ __launch_bounds__(256) void transpose_cvt(const float *__restrict__ src,
                                                     __hip_bfloat16 *__restrict__ dst,
                                                     int R, int C) {
  __shared__ float tile[64][65];
  const int e = blockIdx.z;
  const int rb = blockIdx.x * 64, cb = blockIdx.y * 64;
  const size_t base = (size_t)e * R * C;
  const int lx = threadIdx.x & 63, ly = threadIdx.x >> 6;
#pragma unroll
  for (int i = 0; i < 64; i += 4)
    tile[ly + i][lx] = src[base + (size_t)(rb + ly + i) * C + cb + lx];
  __syncthreads();
  const int l = threadIdx.x & 15;   // 16 lanes x 4 elems cover one output row
  const int j0 = threadIdx.x >> 4;  // 16 output rows per pass
#pragma unroll
  for (int i = 0; i < 64; i += 16) {
    const int j = j0 + i;
    union { __hip_bfloat16 h[4]; uint2 u; } pk;
#pragma unroll
    for (int k = 0; k < 4; ++k) pk.h[k] = __float2bfloat16(tile[4 * l + k][j]);
    *(uint2 *)(dst + base + (size_t)(cb + j) * R + rb + 4 * l) = pk.u;
  }
}

// ---------------- router (fp64 accumulation: exact top-2 match) --------------
// fused x fp32->bf16 conversion (float4 reads, bf16x4 writes)
__global__ __launch_bounds__(256) void router_k(const float *__restrict__ x,
                                                const float *__restrict__ Wg,
                                                int *__restrict__ counts,
                                                float *__restrict__ probsum,
                                                int *__restrict__ tok_e,
                                                float *__restrict__ tok_w,
                                                __hip_bfloat16 *__restrict__ xb) {
  __shared__ float sprob[NEXP];
  __shared__ int scnt[NEXP];
  if (threadIdx.x < NEXP) { sprob[threadIdx.x] = 0.f; scnt[threadIdx.x] = 0; }
  __syncthreads();

  const int wid = threadIdx.x >> 6, lane = threadIdx.x & 63;
  const int t = blockIdx.x * 4 + wid;
  const float *xr = x + (size_t)t * DDIM;
  __hip_bfloat16 *xbr = xb + (size_t)t * DDIM;
  double acc[NEXP];
#pragma unroll
  for (int e = 0; e < NEXP; ++e) acc[e] = 0.0;
#pragma unroll
  for (int it = 0; it < DDIM / 256; ++it) {
    const int j = it * 256 + lane * 4;
    float4 v = *(const float4 *)(xr + j);
    float vv[4] = {v.x, v.y, v.z, v.w};
    union { __hip_bfloat16 h[4]; uint2 u; } pk;
#pragma unroll
    for (int u = 0; u < 4; ++u) pk.h[u] = __float2bfloat16(vv[u]);
    *(uint2 *)(xbr + j) = pk.u;
    const float *w0 = Wg + (size_t)j * NEXP;
#pragma unroll
    for (int u = 0; u < 4; ++u) {
      double xv = (double)vv[u];
#pragma unroll
      for (int e = 0; e < NEXP; ++e) acc[e] += xv * (double)w0[u * NEXP + e];
    }
  }
#pragma unroll
  for (int e = 0; e < NEXP; ++e) {
#pragma unroll
    for (int off = 32; off > 0; off >>= 1) acc[e] += __shfl_xor(acc[e], off, 64);
  }
  if (lane == 0) {
    double mx = acc[0];
    for (int e = 1; e < NEXP; ++e) mx = acc[e] > mx ? acc[e] : mx;
    double p[NEXP], s = 0.0;
    for (int e = 0; e < NEXP; ++e) { p[e] = exp(acc[e] - mx); s += p[e]; }
    for (int e = 0; e < NEXP; ++e) p[e] /= s;
    int i0 = 0;
    for (int e = 1; e < NEXP; ++e) if (p[e] > p[i0]) i0 = e;
    int i1 = (i0 == 0) ? 1 : 0;
    for (int e = 0; e < NEXP; ++e) if (e != i0 && p[e] > p[i1]) i1 = e;
    tok_e[t] = i0 | (i1 << 16);
    tok_w[t] = (float)(p[i0] / (p[i0] + p[i1]));
    atomicAdd(&scnt[i0], 1);
    atomicAdd(&scnt[i1], 1);
    for (int e = 0; e < NEXP; ++e) atomicAdd(&sprob[e], (float)p[e]);
  }
  __syncthreads();
  if (threadIdx.x < NEXP) {
    atomicAdd(&counts[threadIdx.x], scnt[threadIdx.x]);
    atomicAdd(&probsum[threadIdx.x], sprob[threadIdx.x]);
  }
}

// ---------------- routing tables (pad to 256) + aux loss ----------------
__global__ __launch_bounds__(256) void offsets_k(const int *__restrict__ counts,
                                                 const float *__restrict__ probsum,
                                                 int *__restrict__ padoff,
                                                 int *__restrict__ tileexp,
                                                 int *__restrict__ total,
                                                 int *__restrict__ slot_tok,
                                                 float *__restrict__ slot_w,
                                                 float *__restrict__ aux_out) {
  __shared__ int sp[NEXP + 1];
  if (threadIdx.x == 0) {
    int off = 0, tt = 0;
    double s = 0.0;
    for (int e = 0; e < NEXP; ++e) {
      s += ((double)counts[e] / (double)TTOK) * ((double)probsum[e] / (double)TTOK);
      sp[e] = off;
      padoff[e] = off;
      int nt = (counts[e] + BMT - 1) >> 8;
      for (int i = 0; i < nt; ++i) tileexp[tt + i] = e;
      tt += nt;
      off += nt << 8;
    }
    sp[NEXP] = off;
    *total = tt;
    *aux_out = (float)((double)NEXP * s);
  }
  __syncthreads();
  for (int e = 0; e < NEXP; ++e) {
    int s0 = sp[e] + counts[e], s1 = sp[e + 1];
    for (int s = s0 + (int)threadIdx.x; s < s1; s += 256) {
      slot_tok[s] = 0;   // pad: token 0 (safe to read), weight 0
      slot_w[s] = 0.f;
    }
  }
}

__global__ __launch_bounds__(256) void assign_k(const int *__restrict__ tok_e,
                                                const float *__restrict__ tok_w,
                                                const int *__restrict__ padoff,
                                                int *__restrict__ cursors,
                                                int *__restrict__ slot_tok,
                                                float *__restrict__ slot_w,
                                                int *__restrict__ slot_of) {
  const int t = blockIdx.x * 256 + threadIdx.x;
  const int ee = tok_e[t];
  const int e0 = ee & 0xffff, e1 = ee >> 16;
  const float w0 = tok_w[t];
  int p0 = atomicAdd(&cursors[e0], 1);
  int s0 = padoff[e0] + p0;
  slot_tok[s0] = t; slot_w[s0] = w0; slot_of[2 * t] = s0;
  int p1 = atomicAdd(&cursors[e1], 1);
  int s1 = padoff[e1] + p1;
  slot_tok[s1] = t; slot_w[s1] = 1.0f - w0; slot_of[2 * t + 1] = s1;
}

// ---------------- grouped GEMM: m97 geometry (R9 loop) + tile-major order ----
// 128x128 tile, BK=64, 4 waves (2x2), per-wave 64x64. SINGLE-buffer 32 KiB
// LDS -> 3-4 blocks/CU; co-resident blocks cover the vmcnt(0) drain (which is
// now mostly L2-latency thanks to tile-major L2 reuse: R10 measured FETCH
// 610->188 MB). Per K-tile: vmcnt(0); bar; 16 ds_read_b128; lgkm0; bar;
// stage(t+1); 32 MFMA. T2 swizzle: 0 conflicts.
template <int KD_, int ND_, bool GELU_, bool GATHER_>
__global__ __launch_bounds__(256, 4) void moe_97(
    const __hip_bfloat16 *__restrict__ A, const __hip_bfloat16 *__restrict__ Bw,
    const float *__restrict__ bias, __hip_bfloat16 *__restrict__ Cout,
    const int *__restrict__ slot_token, const int *__restrict__ tile_expert,
    const int *__restrict__ total_tiles) {
  constexpr int nkt = KD_ / 64;
  __shared__ __align__(16) char lsA[128 * 128];  // [128 rows][64 k] bf16
  __shared__ __align__(16) char lsB[128 * 128];

  // T1 XCD chunking (grid total % 8 == 0) + tile-major (ncol fastest) order:
  // consecutive rid in an XCD chunk share the A tile -> L2 reuse (R10: -70% FETCH).
  const int nbx = gridDim.x, ncols = gridDim.y;
  const int fid = blockIdx.y * nbx + blockIdx.x;
  const int q8 = (nbx * ncols) >> 3;
  const int rid = (fid & 7) * q8 + (fid >> 3);
  const int tile = rid / ncols;
  const int ncol = (rid % ncols) * 128;
  if (tile >= ((*total_tiles) << 1)) return;  // whole block exits: no barrier risk
  const int e = tile_expert[tile >> 1];

  const int tid = threadIdx.x;
  const int wid = tid >> 6, lane = tid & 63;
  const int sr = tid >> 3;                      // staging row 0..31 per chunk
  const int scs = (((tid & 7) ^ (sr & 7)) * 8); // T2 pre-swizzled source col (elems)
  const __hip_bfloat16 *Bb = Bw + (size_t)e * ((size_t)ND_ * KD_);
  const __hip_bfloat16 *ap[4], *bp[4];
#pragma unroll
  for (int c = 0; c < 4; ++c) {
    int r = tile * 128 + c * 32 + sr;
    int row = GATHER_ ? slot_token[r] : r;
    ap[c] = A + (size_t)row * KD_ + scs;
    bp[c] = Bb + (size_t)(ncol + c * 32 + sr) * KD_ + scs;
  }

  const int wr = wid >> 1, wc = wid & 1;        // 2x2 wave grid, 64x64 each
  const int ln15 = lane & 15, g4 = lane >> 4;
  int xsl[2];
#pragma unroll
  for (int kc = 0; kc < 2; ++kc) xsl[kc] = ((kc * 4 + g4) ^ (ln15 & 7)) << 4;
  const int abase = (wr * 64 + ln15) * 128;     // + mi*2048 + xsl[kc]
  const int bbase = (wc * 64 + ln15) * 128;     // + nf*2048 + xsl[kc]

  auto STAGE = [&](int kt) {
#pragma unroll
    for (int c = 0; c < 4; ++c) {
      gload16(ap[c] + kt * 64, lsA + c * 4096 + tid * 16);
      gload16(bp[c] + kt * 64, lsB + c * 4096 + tid * 16);
    }
  };

  f32x4 acc[4][4] = {};

  asm volatile("s_waitcnt vmcnt(0)" ::: "memory");  // retire gather/setup loads
  STAGE(0);

  for (int kt = 0; kt < nkt; ++kt) {
    asm volatile("s_waitcnt vmcnt(0)" ::: "memory");  // own staged loads landed
    __builtin_amdgcn_s_barrier();                     // everyone's landed

    bf16x8 ar[4][2], br[4][2];
#pragma unroll
    for (int mi = 0; mi < 4; ++mi)
#pragma unroll
      for (int kc = 0; kc < 2; ++kc)
        ar[mi][kc] = *(const bf16x8 *)(lsA + abase + mi * 2048 + xsl[kc]);
#pragma unroll
    for (int nf = 0; nf < 4; ++nf)
#pragma unroll
      for (int kc = 0; kc < 2; ++kc)
        br[nf][kc] = *(const bf16x8 *)(lsB + bbase + nf * 2048 + xsl[kc]);

    asm volatile("s_waitcnt lgkmcnt(0)" ::: "memory");  // frags in regs
    __builtin_amdgcn_sched_barrier(0);                  // rule #18
    __builtin_amdgcn_s_barrier();                       // all waves done reading

    if (kt + 1 < nkt) STAGE(kt + 1);  // async overwrite; latency under MFMA
    __builtin_amdgcn_sched_barrier(0);

#pragma unroll
    for (int mi = 0; mi < 4; ++mi)
#pragma unroll
      for (int nf = 0; nf < 4; ++nf) {
        acc[mi][nf] = __builtin_amdgcn_mfma_f32_16x16x32_bf16(ar[mi][0], br[nf][0],
                                                              acc[mi][nf], 0, 0, 0);
        acc[mi][nf] = __builtin_amdgcn_mfma_f32_16x16x32_bf16(ar[mi][1], br[nf][1],
                                                              acc[mi][nf], 0, 0, 0);
      }
  }

  // epilogue: C/D layout col=lane&15, row=(lane>>4)*4+reg [m89]
  const float *be = bias + (size_t)e * ND_;
  const int colb = ncol + wc * 64 + ln15;
  float bv[4];
#pragma unroll
  for (int nf = 0; nf < 4; ++nf) bv[nf] = be[colb + nf * 16];
#pragma unroll
  for (int mi = 0; mi < 4; ++mi) {
    const int row0 = tile * 128 + wr * 64 + mi * 16 + g4 * 4;
#pragma unroll
    for (int nf = 0; nf < 4; ++nf) {
      const int col = colb + nf * 16;
#pragma unroll
      for (int r = 0; r < 4; ++r) {
        float v = acc[mi][nf][r] + bv[nf];
        if constexpr (GELU_) v = gelu_f(v);
        Cout[(size_t)(row0 + r) * ND_ + col] = __float2bfloat16(v);
      }
    }
  }
}

// ---------------- combine ----------------
__global__ __launch_bounds__(256) void combine_k(const __hip_bfloat16 *__restrict__ yb,
                                                 const int *__restrict__ slot_of,
                                                 const float *__restrict__ slot_w,
                                                 float *__restrict__ out) {
  const int t = blockIdx.x;
  const int s0 = slot_of[2 * t], s1 = slot_of[2 * t + 1];
  const float w0 = slot_w[s0], w1 = slot_w[s1];
  const unsigned short *y = (const unsigned short *)yb;
  const int c = threadIdx.x * 4;
  ushort4 a = *(const ushort4 *)(y + (size_t)s0 * DDIM + c);
  ushort4 b = *(const ushort4 *)(y + (size_t)s1 * DDIM + c);
  float4 r;
  r.x = w0 * __uint_as_float((unsigned)a.x << 16) + w1 * __uint_as_float((unsigned)b.x << 16);
  r.y = w0 * __uint_as_float((unsigned)a.y << 16) + w1 * __uint_as_float((unsigned)b.y << 16);
  r.z = w0 * __uint_as_float((unsigned)a.z << 16) + w1 * __uint_as_float((unsigned)b.z << 16);
  r.w = w0 * __uint_as_float((unsigned)a.w << 16) + w1 * __uint_as_float((unsigned)b.w << 16);
  *(float4 *)(out + (size_t)t * DDIM + c) = r;
}

// ---------------- launch ----------------
extern "C" void kernel_launch(void *const *d_in, const int *in_sizes, int n_in,
                              void *d_out, int out_size, void *d_ws, size_t ws_size,
                              hipStream_t stream) {
  const float *x  = (const float *)d_in[0];
  const float *Wg = (const float *)d_in[1];
  const float *W1 = (const float *)d_in[2];
  const float *b1 = (const float *)d_in[3];
  const float *W2 = (const float *)d_in[4];
  const float *b2 = (const float *)d_in[5];
  float *out = (float *)d_out;

  char *ws = (char *)d_ws;
  const size_t MB = 1ull << 20;
  int   *counts   = (int *)(ws + 0);
  int   *cursors  = (int *)(ws + 64);
  int   *padoff   = (int *)(ws + 128);
  int   *tileexp  = (int *)(ws + 192);
  int   *total    = (int *)(ws + 768);
  float *probsum  = (float *)(ws + 832);
  int   *tok_e    = (int *)(ws + 4096);
  float *tok_w    = (float *)(ws + 36864);
  int   *slot_tok = (int *)(ws + 69632);
  float *slot_w   = (float *)(ws + 147456);
  int   *slot_of  = (int *)(ws + 225280);
  __hip_bfloat16 *xb  = (__hip_bfloat16 *)(ws + 1 * MB);    // 16 MiB  [T][D]
  __hip_bfloat16 *w1t = (__hip_bfloat16 *)(ws + 17 * MB);   // 64 MiB  [E][H][D]
  __hip_bfloat16 *hb  = (__hip_bfloat16 *)(ws + 81 * MB);   // 144 MiB [MAXSLOTS][H]
  __hip_bfloat16 *w2t = (__hip_bfloat16 *)(ws + 1 * MB);    // 64 MiB  [E][D][H] (xb/w1t dead)
  __hip_bfloat16 *yb  = (__hip_bfloat16 *)(ws + 225 * MB);  // 36 MiB  [MAXSLOTS][D]

  zero_meta<<<1, 64, 0, stream>>>(counts, cursors, probsum);
  router_k<<<TTOK / 4, 256, 0, stream>>>(x, Wg, counts, probsum, tok_e, tok_w, xb);
  transpose_cvt<<<dim3(16, 64, 8), 256, 0, stream>>>(W1, w1t, DDIM, HDIM);
  offsets_k<<<1, 256, 0, stream>>>(counts, probsum, padoff, tileexp, total,
                                   slot_tok, slot_w, out + (size_t)TTOK * DDIM);
  assign_k<<<TTOK / 256, 256, 0, stream>>>(tok_e, tok_w, padoff, cursors, slot_tok, slot_w, slot_of);
  // GEMM1: h = gelu(x@W1+b1): 128x128 tiles, grid 144x32 = 4608 blocks
  moe_97<DDIM, HDIM, true, true><<<dim3(2 * MAXT, HDIM / 128), 256, 0, stream>>>(
      xb, w1t, b1, hb, slot_tok, tileexp, total);
  transpose_cvt<<<dim3(64, 16, 8), 256, 0, stream>>>(W2, w2t, HDIM, DDIM);
  // GEMM2: y = h@W2+b2: 128x128 tiles, grid 144x8 = 1152 blocks
  moe_97<HDIM, DDIM, false, false><<<dim3(2 * MAXT, DDIM / 128), 256, 0, stream>>>(
      hb, w2t, b2, yb, slot_tok, tileexp, total);
  combine_k<<<TTOK, 256, 0, stream>>>(yb, slot_of, slot_w, out);
}

// Round 12
// 548.537 us; speedup vs baseline: 3.0281x; 3.0281x over previous
//
#include <hip/hip_runtime.h>
#include <hip/hip_bf16.h>
#include <math.h>

#define TTOK 8192
#define DDIM 1024
#define HDIM 4096
#define NEXP 8
#define BMT 256              // slot padding granularity per expert
#define MAXT 72              // sum ceil(c_e/256) <= 16384/256 + 8
#define MAXSLOTS (MAXT * BMT)

typedef __bf16 bf16x8 __attribute__((ext_vector_type(8)));
typedef float f32x4 __attribute__((ext_vector_type(4)));
typedef const void __attribute__((address_space(1))) *gvp_t;
typedef void __attribute__((address_space(3))) *lvp_t;

__device__ __forceinline__ void gload16(const void *g, void *l) {
  __builtin_amdgcn_global_load_lds((gvp_t)g, (lvp_t)l, 16, 0, 0);
}

// fast exact-erf GELU: Abramowitz-Stegun 7.1.26, |err(erf)| <= 1.5e-7
__device__ __forceinline__ float gelu_f(float v) {
  const float z = v * 0.70710678118654752f;
  const float az = fabsf(z);
  const float t = __builtin_amdgcn_rcpf(fmaf(0.3275911f, az, 1.0f));
  float p = fmaf(1.061405429f, t, -1.453152027f);
  p = fmaf(p, t, 1.421413741f);
  p = fmaf(p, t, -0.284496736f);
  p = fmaf(p, t, 0.254829592f);
  p *= t;
  const float ez = __builtin_amdgcn_exp2f(az * az * -1.4426950408889634f);
  float r = fmaf(-p, ez, 1.0f);          // erf(|z|)
  r = (v < 0.f) ? -r : r;                // erf(z)
  return 0.5f * v * (1.0f + r);
}

// ---------------- small utility kernels ----------------

__global__ __launch_bounds__(64) void zero_meta(int *counts, int *cursors, float *probsum) {
  int i = threadIdx.x;
  if (i < NEXP) { counts[i] = 0; cursors[i] = 0; probsum[i] = 0.f; }
}

// src [E][R][C] fp32 -> dst [E][C][R] bf16, 64x64 LDS tiles.
// Writes vectorized: uint2 = 4 bf16 per lane (G13); LDS reads <=2-way (free).
__global__ __launch_bounds__(256) void transpose_cvt(const float *__restrict__ src,
                                                     __hip_bfloat16 *__restrict__ dst,
                                                     int R, int C) {
  __shared__ float tile[64][65];
  const int e = blockIdx.z;
  const int rb = blockIdx.x * 64, cb = blockIdx.y * 64;
  const size_t base = (size_t)e * R * C;
  const int lx = threadIdx.x & 63, ly = threadIdx.x >> 6;
#pragma unroll
  for (int i = 0; i < 64; i += 4)
    tile[ly + i][lx] = src[base + (size_t)(rb + ly + i) * C + cb + lx];
  __syncthreads();
  const int l = threadIdx.x & 15;   // 16 lanes x 4 elems cover one output row
  const int j0 = threadIdx.x >> 4;  // 16 output rows per pass
#pragma unroll
  for (int i = 0; i < 64; i += 16) {
    const int j = j0 + i;
    union { __hip_bfloat16 h[4]; uint2 u; } pk;
#pragma unroll
    for (int k = 0; k < 4; ++k) pk.h[k] = __float2bfloat16(tile[4 * l + k][j]);
    *(uint2 *)(dst + base + (size_t)(cb + j) * R + rb + 4 * l) = pk.u;
  }
}

// ---------------- router (fp64 accumulation: exact top-2 match) --------------
// fused x fp32->bf16 conversion (float4 reads, bf16x4 writes)
__global__ __launch_bounds__(256) void router_k(const float *__restrict__ x,
                                                const float *__restrict__ Wg,
                                                int *__restrict__ counts,
                                                float *__restrict__ probsum,
                                                int *__restrict__ tok_e,
                                                float *__restrict__ tok_w,
                                                __hip_bfloat16 *__restrict__ xb) {
  __shared__ float sprob[NEXP];
  __shared__ int scnt[NEXP];
  if (threadIdx.x < NEXP) { sprob[threadIdx.x] = 0.f; scnt[threadIdx.x] = 0; }
  __syncthreads();

  const int wid = threadIdx.x >> 6, lane = threadIdx.x & 63;
  const int t = blockIdx.x * 4 + wid;
  const float *xr = x + (size_t)t * DDIM;
  __hip_bfloat16 *xbr = xb + (size_t)t * DDIM;
  double acc[NEXP];
#pragma unroll
  for (int e = 0; e < NEXP; ++e) acc[e] = 0.0;
#pragma unroll
  for (int it = 0; it < DDIM / 256; ++it) {
    const int j = it * 256 + lane * 4;
    float4 v = *(const float4 *)(xr + j);
    float vv[4] = {v.x, v.y, v.z, v.w};
    union { __hip_bfloat16 h[4]; uint2 u; } pk;
#pragma unroll
    for (int u = 0; u < 4; ++u) pk.h[u] = __float2bfloat16(vv[u]);
    *(uint2 *)(xbr + j) = pk.u;
    const float *w0 = Wg + (size_t)j * NEXP;
#pragma unroll
    for (int u = 0; u < 4; ++u) {
      double xv = (double)vv[u];
#pragma unroll
      for (int e = 0; e < NEXP; ++e) acc[e] += xv * (double)w0[u * NEXP + e];
    }
  }
#pragma unroll
  for (int e = 0; e < NEXP; ++e) {
#pragma unroll
    for (int off = 32; off > 0; off >>= 1) acc[e] += __shfl_xor(acc[e], off, 64);
  }
  if (lane == 0) {
    double mx = acc[0];
    for (int e = 1; e < NEXP; ++e) mx = acc[e] > mx ? acc[e] : mx;
    double p[NEXP], s = 0.0;
    for (int e = 0; e < NEXP; ++e) { p[e] = exp(acc[e] - mx); s += p[e]; }
    for (int e = 0; e < NEXP; ++e) p[e] /= s;
    int i0 = 0;
    for (int e = 1; e < NEXP; ++e) if (p[e] > p[i0]) i0 = e;
    int i1 = (i0 == 0) ? 1 : 0;
    for (int e = 0; e < NEXP; ++e) if (e != i0 && p[e] > p[i1]) i1 = e;
    tok_e[t] = i0 | (i1 << 16);
    tok_w[t] = (float)(p[i0] / (p[i0] + p[i1]));
    atomicAdd(&scnt[i0], 1);
    atomicAdd(&scnt[i1], 1);
    for (int e = 0; e < NEXP; ++e) atomicAdd(&sprob[e], (float)p[e]);
  }
  __syncthreads();
  if (threadIdx.x < NEXP) {
    atomicAdd(&counts[threadIdx.x], scnt[threadIdx.x]);
    atomicAdd(&probsum[threadIdx.x], sprob[threadIdx.x]);
  }
}

// ---------------- routing tables (pad to 256) + aux loss ----------------
__global__ __launch_bounds__(256) void offsets_k(const int *__restrict__ counts,
                                                 const float *__restrict__ probsum,
                                                 int *__restrict__ padoff,
                                                 int *__restrict__ tileexp,
                                                 int *__restrict__ total,
                                                 int *__restrict__ slot_tok,
                                                 float *__restrict__ slot_w,
                                                 float *__restrict__ aux_out) {
  __shared__ int sp[NEXP + 1];
  if (threadIdx.x == 0) {
    int off = 0, tt = 0;
    double s = 0.0;
    for (int e = 0; e < NEXP; ++e) {
      s += ((double)counts[e] / (double)TTOK) * ((double)probsum[e] / (double)TTOK);
      sp[e] = off;
      padoff[e] = off;
      int nt = (counts[e] + BMT - 1) >> 8;
      for (int i = 0; i < nt; ++i) tileexp[tt + i] = e;
      tt += nt;
      off += nt << 8;
    }
    sp[NEXP] = off;
    *total = tt;
    *aux_out = (float)((double)NEXP * s);
  }
  __syncthreads();
  for (int e = 0; e < NEXP; ++e) {
    int s0 = sp[e] + counts[e], s1 = sp[e + 1];
    for (int s = s0 + (int)threadIdx.x; s < s1; s += 256) {
      slot_tok[s] = 0;   // pad: token 0 (safe to read), weight 0
      slot_w[s] = 0.f;
    }
  }
}

__global__ __launch_bounds__(256) void assign_k(const int *__restrict__ tok_e,
                                                const float *__restrict__ tok_w,
                                                const int *__restrict__ padoff,
                                                int *__restrict__ cursors,
                                                int *__restrict__ slot_tok,
                                                float *__restrict__ slot_w,
                                                int *__restrict__ slot_of) {
  const int t = blockIdx.x * 256 + threadIdx.x;
  const int ee = tok_e[t];
  const int e0 = ee & 0xffff, e1 = ee >> 16;
  const float w0 = tok_w[t];
  int p0 = atomicAdd(&cursors[e0], 1);
  int s0 = padoff[e0] + p0;
  slot_tok[s0] = t; slot_w[s0] = w0; slot_of[2 * t] = s0;
  int p1 = atomicAdd(&cursors[e1], 1);
  int s1 = padoff[e1] + p1;
  slot_tok[s1] = t; slot_w[s1] = 1.0f - w0; slot_of[2 * t + 1] = s1;
}

// ---------------- grouped GEMM: m97 geometry (R9 loop) + tile-major order ----
// 128x128 tile, BK=64, 4 waves (2x2), per-wave 64x64. SINGLE-buffer 32 KiB
// LDS, __launch_bounds__(256,3) -> 84 VGPR, NO SPILL (empirical: >=4 spills,
// R6/R11). 3 blocks/CU cover the vmcnt(0) drain, which is mostly L2 latency
// thanks to tile-major L2 reuse (R10: FETCH 610->188 MB).
// Per K-tile: vmcnt(0); bar; 16 ds_read_b128; lgkm0; bar; stage(t+1); 32 MFMA.
template <int KD_, int ND_, bool GELU_, bool GATHER_>
__global__ __launch_bounds__(256, 3) void moe_97(
    const __hip_bfloat16 *__restrict__ A, const __hip_bfloat16 *__restrict__ Bw,
    const float *__restrict__ bias, __hip_bfloat16 *__restrict__ Cout,
    const int *__restrict__ slot_token, const int *__restrict__ tile_expert,
    const int *__restrict__ total_tiles) {
  constexpr int nkt = KD_ / 64;
  __shared__ __align__(16) char lsA[128 * 128];  // [128 rows][64 k] bf16
  __shared__ __align__(16) char lsB[128 * 128];

  // T1 XCD chunking (grid total % 8 == 0) + tile-major (ncol fastest) order:
  // consecutive rid in an XCD chunk share the A tile -> L2 reuse (R10: -70% FETCH).
  const int nbx = gridDim.x, ncols = gridDim.y;
  const int fid = blockIdx.y * nbx + blockIdx.x;
  const int q8 = (nbx * ncols) >> 3;
  const int rid = (fid & 7) * q8 + (fid >> 3);
  const int tile = rid / ncols;
  const int ncol = (rid % ncols) * 128;
  if (tile >= ((*total_tiles) << 1)) return;  // whole block exits: no barrier risk
  const int e = tile_expert[tile >> 1];

  const int tid = threadIdx.x;
  const int wid = tid >> 6, lane = tid & 63;
  const int sr = tid >> 3;                      // staging row 0..31 per chunk
  const int scs = (((tid & 7) ^ (sr & 7)) * 8); // T2 pre-swizzled source col (elems)
  const __hip_bfloat16 *Bb = Bw + (size_t)e * ((size_t)ND_ * KD_);
  const __hip_bfloat16 *ap[4], *bp[4];
#pragma unroll
  for (int c = 0; c < 4; ++c) {
    int r = tile * 128 + c * 32 + sr;
    int row = GATHER_ ? slot_token[r] : r;
    ap[c] = A + (size_t)row * KD_ + scs;
    bp[c] = Bb + (size_t)(ncol + c * 32 + sr) * KD_ + scs;
  }

  const int wr = wid >> 1, wc = wid & 1;        // 2x2 wave grid, 64x64 each
  const int ln15 = lane & 15, g4 = lane >> 4;
  int xsl[2];
#pragma unroll
  for (int kc = 0; kc < 2; ++kc) xsl[kc] = ((kc * 4 + g4) ^ (ln15 & 7)) << 4;
  const int abase = (wr * 64 + ln15) * 128;     // + mi*2048 + xsl[kc]
  const int bbase = (wc * 64 + ln15) * 128;     // + nf*2048 + xsl[kc]

  auto STAGE = [&](int kt) {
#pragma unroll
    for (int c = 0; c < 4; ++c) {
      gload16(ap[c] + kt * 64, lsA + c * 4096 + tid * 16);
      gload16(bp[c] + kt * 64, lsB + c * 4096 + tid * 16);
    }
  };

  f32x4 acc[4][4] = {};

  asm volatile("s_waitcnt vmcnt(0)" ::: "memory");  // retire gather/setup loads
  STAGE(0);

  for (int kt = 0; kt < nkt; ++kt) {
    asm volatile("s_waitcnt vmcnt(0)" ::: "memory");  // own staged loads landed
    __builtin_amdgcn_s_barrier();                     // everyone's landed

    bf16x8 ar[4][2], br[4][2];
#pragma unroll
    for (int mi = 0; mi < 4; ++mi)
#pragma unroll
      for (int kc = 0; kc < 2; ++kc)
        ar[mi][kc] = *(const bf16x8 *)(lsA + abase + mi * 2048 + xsl[kc]);
#pragma unroll
    for (int nf = 0; nf < 4; ++nf)
#pragma unroll
      for (int kc = 0; kc < 2; ++kc)
        br[nf][kc] = *(const bf16x8 *)(lsB + bbase + nf * 2048 + xsl[kc]);

    asm volatile("s_waitcnt lgkmcnt(0)" ::: "memory");  // frags in regs
    __builtin_amdgcn_sched_barrier(0);                  // rule #18
    __builtin_amdgcn_s_barrier();                       // all waves done reading

    if (kt + 1 < nkt) STAGE(kt + 1);  // async overwrite; latency under MFMA
    __builtin_amdgcn_sched_barrier(0);

#pragma unroll
    for (int mi = 0; mi < 4; ++mi)
#pragma unroll
      for (int nf = 0; nf < 4; ++nf) {
        acc[mi][nf] = __builtin_amdgcn_mfma_f32_16x16x32_bf16(ar[mi][0], br[nf][0],
                                                              acc[mi][nf], 0, 0, 0);
        acc[mi][nf] = __builtin_amdgcn_mfma_f32_16x16x32_bf16(ar[mi][1], br[nf][1],
                                                              acc[mi][nf], 0, 0, 0);
      }
  }

  // epilogue: C/D layout col=lane&15, row=(lane>>4)*4+reg [m89]
  const float *be = bias + (size_t)e * ND_;
  const int colb = ncol + wc * 64 + ln15;
  float bv[4];
#pragma unroll
  for (int nf = 0; nf < 4; ++nf) bv[nf] = be[colb + nf * 16];
#pragma unroll
  for (int mi = 0; mi < 4; ++mi) {
    const int row0 = tile * 128 + wr * 64 + mi * 16 + g4 * 4;
#pragma unroll
    for (int nf = 0; nf < 4; ++nf) {
      const int col = colb + nf * 16;
#pragma unroll
      for (int r = 0; r < 4; ++r) {
        float v = acc[mi][nf][r] + bv[nf];
        if constexpr (GELU_) v = gelu_f(v);
        Cout[(size_t)(row0 + r) * ND_ + col] = __float2bfloat16(v);
      }
    }
  }
}

// ---------------- combine ----------------
__global__ __launch_bounds__(256) void combine_k(const __hip_bfloat16 *__restrict__ yb,
                                                 const int *__restrict__ slot_of,
                                                 const float *__restrict__ slot_w,
                                                 float *__restrict__ out) {
  const int t = blockIdx.x;
  const int s0 = slot_of[2 * t], s1 = slot_of[2 * t + 1];
  const float w0 = slot_w[s0], w1 = slot_w[s1];
  const unsigned short *y = (const unsigned short *)yb;
  const int c = threadIdx.x * 4;
  ushort4 a = *(const ushort4 *)(y + (size_t)s0 * DDIM + c);
  ushort4 b = *(const ushort4 *)(y + (size_t)s1 * DDIM + c);
  float4 r;
  r.x = w0 * __uint_as_float((unsigned)a.x << 16) + w1 * __uint_as_float((unsigned)b.x << 16);
  r.y = w0 * __uint_as_float((unsigned)a.y << 16) + w1 * __uint_as_float((unsigned)b.y << 16);
  r.z = w0 * __uint_as_float((unsigned)a.z << 16) + w1 * __uint_as_float((unsigned)b.z << 16);
  r.w = w0 * __uint_as_float((unsigned)a.w << 16) + w1 * __uint_as_float((unsigned)b.w << 16);
  *(float4 *)(out + (size_t)t * DDIM + c) = r;
}

// ---------------- launch ----------------
extern "C" void kernel_launch(void *const *d_in, const int *in_sizes, int n_in,
                              void *d_out, int out_size, void *d_ws, size_t ws_size,
                              hipStream_t stream) {
  const float *x  = (const float *)d_in[0];
  const float *Wg = (const float *)d_in[1];
  const float *W1 = (const float *)d_in[2];
  const float *b1 = (const float *)d_in[3];
  const float *W2 = (const float *)d_in[4];
  const float *b2 = (const float *)d_in[5];
  float *out = (float *)d_out;

  char *ws = (char *)d_ws;
  const size_t MB = 1ull << 20;
  int   *counts   = (int *)(ws + 0);
  int   *cursors  = (int *)(ws + 64);
  int   *padoff   = (int *)(ws + 128);
  int   *tileexp  = (int *)(ws + 192);
  int   *total    = (int *)(ws + 768);
  float *probsum  = (float *)(ws + 832);
  int   *tok_e    = (int *)(ws + 4096);
  float *tok_w    = (float *)(ws + 36864);
  int   *slot_tok = (int *)(ws + 69632);
  float *slot_w   = (float *)(ws + 147456);
  int   *slot_of  = (int *)(ws + 225280);
  __hip_bfloat16 *xb  = (__hip_bfloat16 *)(ws + 1 * MB);    // 16 MiB  [T][D]
  __hip_bfloat16 *w1t = (__hip_bfloat16 *)(ws + 17 * MB);   // 64 MiB  [E][H][D]
  __hip_bfloat16 *hb  = (__hip_bfloat16 *)(ws + 81 * MB);   // 144 MiB [MAXSLOTS][H]
  __hip_bfloat16 *w2t = (__hip_bfloat16 *)(ws + 1 * MB);    // 64 MiB  [E][D][H] (xb/w1t dead)
  __hip_bfloat16 *yb  = (__hip_bfloat16 *)(ws + 225 * MB);  // 36 MiB  [MAXSLOTS][D]

  zero_meta<<<1, 64, 0, stream>>>(counts, cursors, probsum);
  router_k<<<TTOK / 4, 256, 0, stream>>>(x, Wg, counts, probsum, tok_e, tok_w, xb);
  transpose_cvt<<<dim3(16, 64, 8), 256, 0, stream>>>(W1, w1t, DDIM, HDIM);
  offsets_k<<<1, 256, 0, stream>>>(counts, probsum, padoff, tileexp, total,
                                   slot_tok, slot_w, out + (size_t)TTOK * DDIM);
  assign_k<<<TTOK / 256, 256, 0, stream>>>(tok_e, tok_w, padoff, cursors, slot_tok, slot_w, slot_of);
  // GEMM1: h = gelu(x@W1+b1): 128x128 tiles, grid 144x32 = 4608 blocks
  moe_97<DDIM, HDIM, true, true><<<dim3(2 * MAXT, HDIM / 128), 256, 0, stream>>>(
      xb, w1t, b1, hb, slot_tok, tileexp, total);
  transpose_cvt<<<dim3(64, 16, 8), 256, 0, stream>>>(W2, w2t, HDIM, DDIM);
  // GEMM2: y = h@W2+b2: 128x128 tiles, grid 144x8 = 1152 blocks
  moe_97<HDIM, DDIM, false, false><<<dim3(2 * MAXT, DDIM / 128), 256, 0, stream>>>(
      hb, w2t, b2, yb, slot_tok, tileexp, total);
  combine_k<<<TTOK, 256, 0, stream>>>(yb, slot_of, slot_w, out);
}